// Round 5
// baseline (1143.423 us; speedup 1.0000x reference)
//
#include <hip/hip_runtime.h>
#include <cstdint>
#include <cstddef>

// 20-qubit statevector sim, fused into ONE kernel: 6 passes (2 per circuit
// block) with flag-based grid barriers between, 512 blocks x 256 threads.
//
// Pass S1(k): U3 q0..q10 + CU3 (0,1)..(9,10); input layout tile bits 0..10 =
//   (q0..q10) ascending, block bits 11..19 = (q11..q19).
// Pass S2(k): U3 q11..q19 + CU3 (10,11)..(19,0); tile = (q10,q11..q19,q0),
//   block = (q1..q9).
// Within a pass: 5 phases; each phase's 3-qubit register window is ALWAYS
// tile bits (0,1,2); between phases the tile is rotated down by 2
// (L' = (L>>2) | ((L&3)<<9)). With PHYS(L)=L+2(L>>4) padding, both the
// contiguous reads (4xb128/thread) and the quadrant rotate-stores
// (4xb128/thread) hit all 32 banks uniformly (verified by hand: bank group
// = (s+w) mod 8 over lane bits) -> conflict-free LDS.
// After 4 rotations the final register layout is rotated by 8; the global
// store permutation to the next pass's layout is computed from that
// (scattered 16B float4 runs -> ~1-2us/pass, reads always contiguous).
// Final pass: x = (0.8*tanh(0.1*2^19*|a|^2))^0.3 in registers, block sums ->
// grid barrier -> total -> subtract mean -> bit-reversed scatter to out.

#define NB 512
#define NT 256
#define PHYS(L) ((L) + 2u * ((L) >> 4))

__device__ __forceinline__ float2 cmadd2(float2 m0, float2 a0, float2 m1, float2 a1) {
  float2 r;
  r.x = m0.x * a0.x - m0.y * a0.y + m1.x * a1.x - m1.y * a1.y;
  r.y = m0.x * a0.y + m0.y * a0.x + m1.x * a1.y + m1.y * a1.x;
  return r;
}

template <int BIT>
__device__ __forceinline__ void applyU3(float2* v, const float2* m) {
  float2 m00 = m[0], m01 = m[1], m10 = m[2], m11 = m[3];
#pragma unroll
  for (int j = 0; j < 8; j++)
    if (!((j >> BIT) & 1)) {
      int j1 = j | (1 << BIT);
      float2 a0 = v[j], a1 = v[j1];
      v[j] = cmadd2(m00, a0, m01, a1);
      v[j1] = cmadd2(m10, a0, m11, a1);
    }
}

template <int C, int T>
__device__ __forceinline__ void applyCU3(float2* v, const float2* m) {
  float2 u00 = m[0], u01 = m[1], u10 = m[2], u11 = m[3];
#pragma unroll
  for (int j = 0; j < 8; j++)
    if (((j >> C) & 1) && !((j >> T) & 1)) {
      int j1 = j | (1 << T);
      float2 a0 = v[j], a1 = v[j1];
      v[j] = cmadd2(u00, a0, u01, a1);
      v[j1] = cmadd2(u10, a0, u11, a1);
    }
}

// One phase on window bits (0,1,2). U*/C* are within-circuit-block gate ids
// (-1 = skip). M: U3 q at [4q], CU3 control c at [80+4c].
template <int U0, int U1, int U2, int C01, int C12>
__device__ __forceinline__ void phase(float2* v, const float2* M) {
  if (U0 >= 0) applyU3<0>(v, M + 4 * (U0 < 0 ? 0 : U0));
  if (U1 >= 0) applyU3<1>(v, M + 4 * (U1 < 0 ? 0 : U1));
  if (U2 >= 0) applyU3<2>(v, M + 4 * (U2 < 0 ? 0 : U2));
  if (C01 >= 0) applyCU3<0, 1>(v, M + 80 + 4 * (C01 < 0 ? 0 : C01));
  if (C12 >= 0) applyCU3<1, 2>(v, M + 80 + 4 * (C12 < 0 ? 0 : C12));
}

// store v (layout L=8t+m) rotated: L' = (L>>2)|((L&3)<<9) = 2t+(m>>2)+(m&3)<<9
__device__ __forceinline__ void rot_store(float2* lds, unsigned t, const float2* v) {
#pragma unroll
  for (int q = 0; q < 4; q++) {
    unsigned Lp = 2u * t + 512u * q;
    *(float4*)&lds[PHYS(Lp)] = make_float4(v[q].x, v[q].y, v[q + 4].x, v[q + 4].y);
  }
}

// contiguous read of the new layout: v[m] = lds[PHYS(8t+m)] (no 16-boundary
// crossing within a thread's 8 amps -> phys-contiguous 64B)
__device__ __forceinline__ void rot_load(const float2* lds, unsigned t, float2* v) {
  const float4* p = (const float4*)&lds[PHYS(8u * t)];
#pragma unroll
  for (int i = 0; i < 4; i++) {
    float4 f = p[i];
    v[2 * i] = make_float2(f.x, f.y);
    v[2 * i + 1] = make_float2(f.z, f.w);
  }
}

__device__ __forceinline__ float xval(float2 a) {
  float p = a.x * a.x + a.y * a.y;
  return powf(0.8f * tanhf(52428.8f * p), 0.3f);
}

__device__ __forceinline__ void gridbar(unsigned* flags, int slot, unsigned b,
                                        unsigned t) {
  __threadfence();   // release own global writes (device scope)
  __syncthreads();
  if (t == 0)
    __hip_atomic_store(&flags[slot * NB + b], 1u, __ATOMIC_RELEASE,
                       __HIP_MEMORY_SCOPE_AGENT);
  unsigned* f0 = &flags[slot * NB + 2 * t];
  int guard = 0;
  while (__hip_atomic_load(f0, __ATOMIC_ACQUIRE, __HIP_MEMORY_SCOPE_AGENT) != 1u ||
         __hip_atomic_load(f0 + 1, __ATOMIC_ACQUIRE, __HIP_MEMORY_SCOPE_AGENT) != 1u) {
    __builtin_amdgcn_s_sleep(2);
    if (++guard > (1 << 20)) break;  // safety valve: fail loud, don't hang
  }
  __threadfence();   // acquire: invalidate L1 so cross-CU data is fresh
  __syncthreads();
}

__device__ __forceinline__ void fill_mats(const float* u3p, const float* cu3p,
                                          int k, unsigned t, float2* M) {
  if (t < 20) {
    const float* s = u3p + (k * 20 + t) * 3;
    float st, ct, sl, cl, sp, cp, spl, cpl;
    sincosf(0.5f * s[0], &st, &ct);
    sincosf(s[2], &sl, &cl);
    sincosf(s[1], &sp, &cp);
    sincosf(s[1] + s[2], &spl, &cpl);
    float2* m = M + 4 * t;
    m[0] = make_float2(ct, 0.f);
    m[1] = make_float2(-cl * st, -sl * st);
    m[2] = make_float2(cp * st, sp * st);
    m[3] = make_float2(cpl * ct, spl * ct);
  } else if (t >= 64 && t < 84) {
    int c = t - 64;
    const float* s = cu3p + (k * 20 + c) * 3;
    float st, ct, sl, cl, sp, cp, spl, cpl;
    sincosf(0.5f * s[0], &st, &ct);
    sincosf(s[2], &sl, &cl);
    sincosf(s[1], &sp, &cp);
    sincosf(s[1] + s[2], &spl, &cpl);
    float2* m = M + 80 + 4 * c;
    m[0] = make_float2(ct, 0.f);
    m[1] = make_float2(-cl * st, -sl * st);
    m[2] = make_float2(cp * st, sp * st);
    m[3] = make_float2(cpl * ct, spl * ct);
  }
}

// TYPE 0 = S1, 1 = S2; INIT synthesizes |0..0>; FINAL does readout.
template <int TYPE, int INIT, int FINAL>
__device__ __forceinline__ void do_pass(int k, const float2* __restrict__ in,
                                        float2* __restrict__ outPsi,
                                        const float* u3p, const float* cu3p,
                                        float2* A, float2* B, float2* M,
                                        float* red, unsigned t, unsigned b,
                                        float* sumArr, unsigned* flags,
                                        float* out) {
  fill_mats(u3p, cu3p, k, t, M);

  float2 v[8];
  if (INIT) {
#pragma unroll
    for (int j = 0; j < 8; j++) v[j] = make_float2(0.f, 0.f);
    if (b == 0 && t == 0) v[0] = make_float2(1.f, 0.f);
  } else {
    const float4* in4 = (const float4*)in + ((size_t)b << 10) + 4u * t;
#pragma unroll
    for (int i = 0; i < 4; i++) {
      float4 f = in4[i];
      v[2 * i] = make_float2(f.x, f.y);
      v[2 * i + 1] = make_float2(f.z, f.w);
    }
  }
  __syncthreads();  // M visible

  if (TYPE == 0) phase<0, 1, 2, 0, 1>(v, M);      else phase<-1, 11, 12, 10, 11>(v, M);
  rot_store(A, t, v); __syncthreads(); rot_load(A, t, v);
  if (TYPE == 0) phase<-1, 3, 4, 2, 3>(v, M);     else phase<-1, 13, 14, 12, 13>(v, M);
  rot_store(B, t, v); __syncthreads(); rot_load(B, t, v);
  if (TYPE == 0) phase<-1, 5, 6, 4, 5>(v, M);     else phase<-1, 15, 16, 14, 15>(v, M);
  rot_store(A, t, v); __syncthreads(); rot_load(A, t, v);
  if (TYPE == 0) phase<-1, 7, 8, 6, 7>(v, M);     else phase<-1, 17, 18, 16, 17>(v, M);
  rot_store(B, t, v); __syncthreads(); rot_load(B, t, v);
  if (TYPE == 0) phase<-1, 9, 10, 8, 9>(v, M);    else phase<-1, 19, -1, 18, 19>(v, M);

  // final register layout (rot by 8): m=(w8,w9,w10), t=(w0..w7) of this
  // pass's chain. Next-pass global index (both directions, by symmetry):
  // f4 = blk + 512*t0 + 1024*(t>>1) + 2^17*m0 + 2^18*m1  (pair over m2)
  if (!FINAL) {
    float4* o4 = (float4*)outPsi;
    unsigned base = b + ((t & 1u) << 9) + ((t >> 1) << 10);
    o4[base] = make_float4(v[0].x, v[0].y, v[4].x, v[4].y);
    o4[base + (1u << 17)] = make_float4(v[1].x, v[1].y, v[5].x, v[5].y);
    o4[base + (1u << 18)] = make_float4(v[2].x, v[2].y, v[6].x, v[6].y);
    o4[base + (3u << 17)] = make_float4(v[3].x, v[3].y, v[7].x, v[7].y);
  } else {
    // S2(2) end: m=(q18,q19,q0), t=(q10..q17), blk=(q1..q9).
    // Reference R: bit 19-q: R = m1 + 2*m0 + 4*rev8(t) + 1024*rev9(b) + 2^19*m2
    float xv[8];
    float s = 0.f;
#pragma unroll
    for (int m = 0; m < 8; m++) { xv[m] = xval(v[m]); s += xv[m]; }
#pragma unroll
    for (int o = 32; o > 0; o >>= 1) s += __shfl_down(s, o);
    if ((t & 63u) == 0) red[t >> 6] = s;
    __syncthreads();
    if (t == 0) sumArr[b] = red[0] + red[1] + red[2] + red[3];
    gridbar(flags, 5, b, t);
    float s2 = sumArr[2 * t] + sumArr[2 * t + 1];
#pragma unroll
    for (int o = 32; o > 0; o >>= 1) s2 += __shfl_down(s2, o);
    __syncthreads();  // red reuse
    if ((t & 63u) == 0) red[t >> 6] = s2;
    __syncthreads();
    float mean = (red[0] + red[1] + red[2] + red[3]) * (1.f / 1048576.f);
    float4* o4 = (float4*)out;
    unsigned base = (__brev(t) >> 24) + ((__brev(b) >> 23) << 8);
    o4[base] = make_float4(xv[0] - mean, xv[2] - mean, xv[1] - mean, xv[3] - mean);
    o4[base + (1u << 17)] =
        make_float4(xv[4] - mean, xv[6] - mean, xv[5] - mean, xv[7] - mean);
  }
}

__global__ __launch_bounds__(NT) void qsim(const float* __restrict__ u3p,
                                           const float* __restrict__ cu3p,
                                           float2* __restrict__ psiA,
                                           float2* __restrict__ psiB,
                                           unsigned* __restrict__ flags,
                                           float* __restrict__ sumArr,
                                           float* __restrict__ out) {
  __shared__ float2 A[2304], B[2304];  // PHYS(2047)=2301
  __shared__ float2 M[160];
  __shared__ float red[8];
  unsigned t = threadIdx.x, b = blockIdx.x;

  if (t < 6) flags[t * NB + b] = 0u;  // zero OWN slots (poison backup)
  __threadfence();

  do_pass<0, 1, 0>(0, nullptr, psiB, u3p, cu3p, A, B, M, red, t, b, sumArr, flags, out);
  gridbar(flags, 0, b, t);
  do_pass<1, 0, 0>(0, psiB, psiA, u3p, cu3p, A, B, M, red, t, b, sumArr, flags, out);
  gridbar(flags, 1, b, t);
  do_pass<0, 0, 0>(1, psiA, psiB, u3p, cu3p, A, B, M, red, t, b, sumArr, flags, out);
  gridbar(flags, 2, b, t);
  do_pass<1, 0, 0>(1, psiB, psiA, u3p, cu3p, A, B, M, red, t, b, sumArr, flags, out);
  gridbar(flags, 3, b, t);
  do_pass<0, 0, 0>(2, psiA, psiB, u3p, cu3p, A, B, M, red, t, b, sumArr, flags, out);
  gridbar(flags, 4, b, t);
  do_pass<1, 0, 1>(2, psiB, nullptr, u3p, cu3p, A, B, M, red, t, b, sumArr, flags, out);
}

extern "C" void kernel_launch(void* const* d_in, const int* in_sizes, int n_in,
                              void* d_out, int out_size, void* d_ws, size_t ws_size,
                              hipStream_t stream) {
  const float* u3p = (const float*)d_in[0];
  const float* cu3p = (const float*)d_in[1];
  float* out = (float*)d_out;

  char* ws = (char*)d_ws;
  float2* psiA = (float2*)ws;                                   // 8 MB
  float2* psiB = (float2*)(ws + (size_t)8 * 1024 * 1024);       // 8 MB
  unsigned* flags = (unsigned*)(ws + (size_t)16 * 1024 * 1024); // 12 KB
  float* sumArr = (float*)(ws + (size_t)16 * 1024 * 1024 + 6 * NB * sizeof(unsigned));

  qsim<<<NB, NT, 0, stream>>>(u3p, cu3p, psiA, psiB, flags, sumArr, out);
}

// Round 6
// 732.987 us; speedup vs baseline: 1.5600x; 1.5600x over previous
//
#include <hip/hip_runtime.h>
#include <cstdint>
#include <cstddef>

// 20-qubit statevector sim, fused into ONE kernel: 6 passes (2 per circuit
// block) with flag-based grid barriers between, 512 blocks x 256 threads.
//
// Pass S1(k): U3 q0..q10 + CU3 (0,1)..(9,10); input layout tile bits 0..10 =
//   (q0..q10) ascending, block bits 11..19 = (q11..q19).
// Pass S2(k): U3 q11..q19 + CU3 (10,11)..(19,0); tile = (q10,q11..q19,q0),
//   block = (q1..q9).
// Within a pass: 5 phases; each phase's 3-qubit register window is ALWAYS
// tile bits (0,1,2); between phases the tile is rotated down by 2
// (L' = (L>>2) | ((L&3)<<9)); LDS double-buffered (A/B), 1 sync per rotation.
// After 4 rotations the final register layout is rotated by 8; the global
// store permutation to the next pass's layout follows from that (16B float4
// scattered stores; reads always contiguous 16 KB tiles).
// Final pass: x = (0.8*tanh(0.1*2^19*|a|^2))^0.3 in registers, block sums ->
// grid barrier -> total -> subtract mean -> bit-reversed scatter to out.
//
// R5 post-mortem: the old barrier had every thread spin on ACQUIRE agent
// loads (each = LLC round-trip + cache-invalidate) -> 22 GB of poll traffic,
// 1.1 ms. New barrier: per-block arrival flags (no RMW contention), polled
// by ONE wave per block with RELAXED agent loads (no invalidate), one
// threadfence after release/exit. Flag "set" value MAGIC != 0xAAAAAAAA
// poison, so no init pass is needed.

#define NB 512
#define NT 256
#define MAGIC 0x1357BDFu
#define PHYS(L) ((L) + 2u * ((L) >> 4))

__device__ __forceinline__ float2 cmadd2(float2 m0, float2 a0, float2 m1, float2 a1) {
  float2 r;
  r.x = m0.x * a0.x - m0.y * a0.y + m1.x * a1.x - m1.y * a1.y;
  r.y = m0.x * a0.y + m0.y * a0.x + m1.x * a1.y + m1.y * a1.x;
  return r;
}

template <int BIT>
__device__ __forceinline__ void applyU3(float2* v, const float2* m) {
  float2 m00 = m[0], m01 = m[1], m10 = m[2], m11 = m[3];
#pragma unroll
  for (int j = 0; j < 8; j++)
    if (!((j >> BIT) & 1)) {
      int j1 = j | (1 << BIT);
      float2 a0 = v[j], a1 = v[j1];
      v[j] = cmadd2(m00, a0, m01, a1);
      v[j1] = cmadd2(m10, a0, m11, a1);
    }
}

template <int C, int T>
__device__ __forceinline__ void applyCU3(float2* v, const float2* m) {
  float2 u00 = m[0], u01 = m[1], u10 = m[2], u11 = m[3];
#pragma unroll
  for (int j = 0; j < 8; j++)
    if (((j >> C) & 1) && !((j >> T) & 1)) {
      int j1 = j | (1 << T);
      float2 a0 = v[j], a1 = v[j1];
      v[j] = cmadd2(u00, a0, u01, a1);
      v[j1] = cmadd2(u10, a0, u11, a1);
    }
}

// One phase on window bits (0,1,2). U*/C* are within-circuit-block gate ids
// (-1 = skip). MU: U3 q at [4q]; MC: CU3 control c at [4c].
template <int U0, int U1, int U2, int C01, int C12>
__device__ __forceinline__ void phase(float2* v, const float2* MU, const float2* MC) {
  if (U0 >= 0) applyU3<0>(v, MU + 4 * (U0 < 0 ? 0 : U0));
  if (U1 >= 0) applyU3<1>(v, MU + 4 * (U1 < 0 ? 0 : U1));
  if (U2 >= 0) applyU3<2>(v, MU + 4 * (U2 < 0 ? 0 : U2));
  if (C01 >= 0) applyCU3<0, 1>(v, MC + 4 * (C01 < 0 ? 0 : C01));
  if (C12 >= 0) applyCU3<1, 2>(v, MC + 4 * (C12 < 0 ? 0 : C12));
}

// store v (layout L=8t+m) rotated: L' = (L>>2)|((L&3)<<9) = 2t+(m>>2)+(m&3)<<9
__device__ __forceinline__ void rot_store(float2* lds, unsigned t, const float2* v) {
#pragma unroll
  for (int q = 0; q < 4; q++) {
    unsigned Lp = 2u * t + 512u * q;
    *(float4*)&lds[PHYS(Lp)] = make_float4(v[q].x, v[q].y, v[q + 4].x, v[q + 4].y);
  }
}

__device__ __forceinline__ void rot_load(const float2* lds, unsigned t, float2* v) {
  const float4* p = (const float4*)&lds[PHYS(8u * t)];
#pragma unroll
  for (int i = 0; i < 4; i++) {
    float4 f = p[i];
    v[2 * i] = make_float2(f.x, f.y);
    v[2 * i + 1] = make_float2(f.z, f.w);
  }
}

__device__ __forceinline__ float xval(float2 a) {
  float p = a.x * a.x + a.y * a.y;
  return powf(0.8f * tanhf(52428.8f * p), 0.3f);
}

// Grid barrier: per-block arrival flags, one polling wave, relaxed polls.
__device__ __forceinline__ void gridbar(unsigned* flags, int slot, unsigned b,
                                        unsigned t) {
  __threadfence();  // release: drain this block's global writes (L2 wb)
  __syncthreads();
  unsigned* base = flags + slot * NB;
  if (t == 0)
    __hip_atomic_store(base + b, MAGIC, __ATOMIC_RELEASE,
                       __HIP_MEMORY_SCOPE_AGENT);
  if (t < 64) {
    unsigned* p = base + 8 * t;
    int guard = 0;
    for (;;) {
      unsigned ok = 1u;
#pragma unroll
      for (int i = 0; i < 8; i++)
        ok &= (__hip_atomic_load(p + i, __ATOMIC_RELAXED,
                                 __HIP_MEMORY_SCOPE_AGENT) == MAGIC);
      if (__all((int)ok)) break;
      if (++guard > (1 << 18)) break;  // fail loud, never hang
      __builtin_amdgcn_s_sleep(2);
    }
  }
  __syncthreads();
  __threadfence();  // acquire: invalidate L1/L2 so remote psi reads are fresh
}

__device__ __forceinline__ void mat_from(const float* s, float2* m) {
  float st, ct, sl, cl, sp, cp, spl, cpl;
  sincosf(0.5f * s[0], &st, &ct);
  sincosf(s[2], &sl, &cl);
  sincosf(s[1], &sp, &cp);
  sincosf(s[1] + s[2], &spl, &cpl);
  m[0] = make_float2(ct, 0.f);
  m[1] = make_float2(-cl * st, -sl * st);
  m[2] = make_float2(cp * st, sp * st);
  m[3] = make_float2(cpl * ct, spl * ct);
}

// TYPE 0 = S1, 1 = S2; INIT synthesizes |0..0>; FINAL does readout.
template <int TYPE, int INIT, int FINAL>
__device__ __forceinline__ void do_pass(int k, const float2* __restrict__ in,
                                        float2* __restrict__ outPsi,
                                        float2* A, float2* B, const float2* Mall,
                                        float* red, unsigned t, unsigned b,
                                        float* sumArr, unsigned* flags,
                                        float* out) {
  const float2* MU = Mall + k * 80;
  const float2* MC = Mall + 240 + k * 80;

  float2 v[8];
  if (INIT) {
#pragma unroll
    for (int j = 0; j < 8; j++) v[j] = make_float2(0.f, 0.f);
    if (b == 0 && t == 0) v[0] = make_float2(1.f, 0.f);
  } else {
    const float4* in4 = (const float4*)in + ((size_t)b << 10) + 4u * t;
#pragma unroll
    for (int i = 0; i < 4; i++) {
      float4 f = in4[i];
      v[2 * i] = make_float2(f.x, f.y);
      v[2 * i + 1] = make_float2(f.z, f.w);
    }
  }

  if (TYPE == 0) phase<0, 1, 2, 0, 1>(v, MU, MC);      else phase<-1, 11, 12, 10, 11>(v, MU, MC);
  rot_store(A, t, v); __syncthreads(); rot_load(A, t, v);
  if (TYPE == 0) phase<-1, 3, 4, 2, 3>(v, MU, MC);     else phase<-1, 13, 14, 12, 13>(v, MU, MC);
  rot_store(B, t, v); __syncthreads(); rot_load(B, t, v);
  if (TYPE == 0) phase<-1, 5, 6, 4, 5>(v, MU, MC);     else phase<-1, 15, 16, 14, 15>(v, MU, MC);
  rot_store(A, t, v); __syncthreads(); rot_load(A, t, v);
  if (TYPE == 0) phase<-1, 7, 8, 6, 7>(v, MU, MC);     else phase<-1, 17, 18, 16, 17>(v, MU, MC);
  rot_store(B, t, v); __syncthreads(); rot_load(B, t, v);
  if (TYPE == 0) phase<-1, 9, 10, 8, 9>(v, MU, MC);    else phase<-1, 19, -1, 18, 19>(v, MU, MC);

  // final register layout (rot by 8): m=(w8,w9,w10), t=(w0..w7) of this
  // pass's chain. Next-pass global index (both directions, by symmetry):
  // f4 = blk + 512*t0 + 1024*(t>>1) + 2^17*m0 + 2^18*m1  (pair over m2)
  if (!FINAL) {
    float4* o4 = (float4*)outPsi;
    unsigned base = b + ((t & 1u) << 9) + ((t >> 1) << 10);
    o4[base] = make_float4(v[0].x, v[0].y, v[4].x, v[4].y);
    o4[base + (1u << 17)] = make_float4(v[1].x, v[1].y, v[5].x, v[5].y);
    o4[base + (1u << 18)] = make_float4(v[2].x, v[2].y, v[6].x, v[6].y);
    o4[base + (3u << 17)] = make_float4(v[3].x, v[3].y, v[7].x, v[7].y);
  } else {
    // S2(2) end: m=(q18,q19,q0), t=(q10..q17), blk=(q1..q9).
    // Reference R (bit 19-q): R = m1 + 2*m0 + 4*rev8(t) + 1024*rev9(b) + 2^19*m2
    float xv[8];
    float s = 0.f;
#pragma unroll
    for (int m = 0; m < 8; m++) { xv[m] = xval(v[m]); s += xv[m]; }
#pragma unroll
    for (int o = 32; o > 0; o >>= 1) s += __shfl_down(s, o);
    if ((t & 63u) == 0) red[t >> 6] = s;
    __syncthreads();
    if (t == 0) sumArr[b] = red[0] + red[1] + red[2] + red[3];
    gridbar(flags, 5, b, t);
    float s2 = sumArr[2 * t] + sumArr[2 * t + 1];
#pragma unroll
    for (int o = 32; o > 0; o >>= 1) s2 += __shfl_down(s2, o);
    __syncthreads();  // red reuse
    if ((t & 63u) == 0) red[t >> 6] = s2;
    __syncthreads();
    float mean = (red[0] + red[1] + red[2] + red[3]) * (1.f / 1048576.f);
    float4* o4 = (float4*)out;
    unsigned base = (__brev(t) >> 24) + ((__brev(b) >> 23) << 8);
    o4[base] = make_float4(xv[0] - mean, xv[2] - mean, xv[1] - mean, xv[3] - mean);
    o4[base + (1u << 17)] =
        make_float4(xv[4] - mean, xv[6] - mean, xv[5] - mean, xv[7] - mean);
  }
}

__global__ __launch_bounds__(NT) void qsim(const float* __restrict__ u3p,
                                           const float* __restrict__ cu3p,
                                           float2* __restrict__ psiA,
                                           float2* __restrict__ psiB,
                                           unsigned* __restrict__ flags,
                                           float* __restrict__ sumArr,
                                           float* __restrict__ out) {
  __shared__ float2 A[2304], B[2304];  // PHYS(2047)=2301
  __shared__ float2 Mall[480];         // 3 blocks x (20 U3 + 20 CU3) x 4
  __shared__ float red[8];
  unsigned t = threadIdx.x, b = blockIdx.x;

  // All gate matrices once: U3 gate g=(k*20+q) -> Mall+4g; CU3 -> Mall+240+4g.
  if (t < 60) mat_from(u3p + 3 * t, Mall + 4 * t);
  else if (t >= 64 && t < 124) mat_from(cu3p + 3 * (t - 64), Mall + 240 + 4 * (t - 64));
  __syncthreads();

  do_pass<0, 1, 0>(0, nullptr, psiB, A, B, Mall, red, t, b, sumArr, flags, out);
  gridbar(flags, 0, b, t);
  do_pass<1, 0, 0>(0, psiB, psiA, A, B, Mall, red, t, b, sumArr, flags, out);
  gridbar(flags, 1, b, t);
  do_pass<0, 0, 0>(1, psiA, psiB, A, B, Mall, red, t, b, sumArr, flags, out);
  gridbar(flags, 2, b, t);
  do_pass<1, 0, 0>(1, psiB, psiA, A, B, Mall, red, t, b, sumArr, flags, out);
  gridbar(flags, 3, b, t);
  do_pass<0, 0, 0>(2, psiA, psiB, A, B, Mall, red, t, b, sumArr, flags, out);
  gridbar(flags, 4, b, t);
  do_pass<1, 0, 1>(2, psiB, nullptr, A, B, Mall, red, t, b, sumArr, flags, out);
}

extern "C" void kernel_launch(void* const* d_in, const int* in_sizes, int n_in,
                              void* d_out, int out_size, void* d_ws, size_t ws_size,
                              hipStream_t stream) {
  const float* u3p = (const float*)d_in[0];
  const float* cu3p = (const float*)d_in[1];
  float* out = (float*)d_out;

  char* ws = (char*)d_ws;
  float2* psiA = (float2*)ws;                                   // 8 MB
  float2* psiB = (float2*)(ws + (size_t)8 * 1024 * 1024);       // 8 MB
  unsigned* flags = (unsigned*)(ws + (size_t)16 * 1024 * 1024); // 12 KB
  float* sumArr = (float*)(ws + (size_t)16 * 1024 * 1024 + 6 * NB * sizeof(unsigned));

  qsim<<<NB, NT, 0, stream>>>(u3p, cu3p, psiA, psiB, flags, sumArr, out);
}

// Round 7
// 135.484 us; speedup vs baseline: 8.4395x; 5.4101x over previous
//
#include <hip/hip_runtime.h>
#include <cstdint>
#include <cstddef>

// 20-qubit statevector sim, 3 layers of [U3 x20 + CU3 ring (0,1)..(19,0)].
// 7 dispatches: 6 tile passes (2 per layer) + tiny mean-subtract kernel.
// In-kernel grid barriers abandoned (R5/R6: software grid-sync costs
// ~100us/barrier on non-coherent-L2 CDNA4 — fence wbl2/inv per block).
// Dispatch boundaries provide coherence at ~10us each instead.
//
// Pass S1(k): U3 q0..q10 + CU3 (0,1)..(9,10); tile bits 0..10 = q0..q10,
//   block bits 11..19 = q11..q19.
// Pass S2(k): U3 q11..q19 + CU3 (10,11)..(19,0); tile = (q10,q11..q19,q0),
//   block = (q1..q9).
// Within a pass: 5 phases, register window always tile bits (0,1,2);
// between phases the tile rotates down by 2 (L' = (L>>2)|((L&3)<<9)),
// LDS double-buffered, 1 sync per rotation, all LDS ops b128.
// After 4 rotations the final register layout is rotated by 8; global
// stores map to the next pass's layout (16B float4 runs; next-pass reads
// are contiguous 16KB tiles). All layout math verified in R5/R6 (passed).
// Final pass: x = (0.8*tanh(0.1*2^19*|a|^2))^0.3 in registers, scattered
// bit-reversed store to out (no mean), block sum -> atomicAdd(accum);
// fin kernel subtracts mean.

#define NB 512
#define NT 256
#define PHYS(L) ((L) + 2u * ((L) >> 4))

__device__ __forceinline__ float2 cmadd2(float2 m0, float2 a0, float2 m1, float2 a1) {
  float2 r;
  r.x = m0.x * a0.x - m0.y * a0.y + m1.x * a1.x - m1.y * a1.y;
  r.y = m0.x * a0.y + m0.y * a0.x + m1.x * a1.y + m1.y * a1.x;
  return r;
}

template <int BIT>
__device__ __forceinline__ void applyU3(float2* v, const float2* m) {
  float2 m00 = m[0], m01 = m[1], m10 = m[2], m11 = m[3];
#pragma unroll
  for (int j = 0; j < 8; j++)
    if (!((j >> BIT) & 1)) {
      int j1 = j | (1 << BIT);
      float2 a0 = v[j], a1 = v[j1];
      v[j] = cmadd2(m00, a0, m01, a1);
      v[j1] = cmadd2(m10, a0, m11, a1);
    }
}

template <int C, int T>
__device__ __forceinline__ void applyCU3(float2* v, const float2* m) {
  float2 u00 = m[0], u01 = m[1], u10 = m[2], u11 = m[3];
#pragma unroll
  for (int j = 0; j < 8; j++)
    if (((j >> C) & 1) && !((j >> T) & 1)) {
      int j1 = j | (1 << T);
      float2 a0 = v[j], a1 = v[j1];
      v[j] = cmadd2(u00, a0, u01, a1);
      v[j1] = cmadd2(u10, a0, u11, a1);
    }
}

// One phase on window bits (0,1,2). U*/C* = within-layer gate ids (-1 = skip).
// MU: U3 qubit q at [4q]; MC: CU3 control c at [4c].
template <int U0, int U1, int U2, int C01, int C12>
__device__ __forceinline__ void phase(float2* v, const float2* MU, const float2* MC) {
  if (U0 >= 0) applyU3<0>(v, MU + 4 * (U0 < 0 ? 0 : U0));
  if (U1 >= 0) applyU3<1>(v, MU + 4 * (U1 < 0 ? 0 : U1));
  if (U2 >= 0) applyU3<2>(v, MU + 4 * (U2 < 0 ? 0 : U2));
  if (C01 >= 0) applyCU3<0, 1>(v, MC + 4 * (C01 < 0 ? 0 : C01));
  if (C12 >= 0) applyCU3<1, 2>(v, MC + 4 * (C12 < 0 ? 0 : C12));
}

// store v (layout L=8t+m) rotated: L' = (L>>2)|((L&3)<<9) = 2t+(m>>2)+(m&3)<<9
__device__ __forceinline__ void rot_store(float2* lds, unsigned t, const float2* v) {
#pragma unroll
  for (int q = 0; q < 4; q++) {
    unsigned Lp = 2u * t + 512u * q;
    *(float4*)&lds[PHYS(Lp)] = make_float4(v[q].x, v[q].y, v[q + 4].x, v[q + 4].y);
  }
}

__device__ __forceinline__ void rot_load(const float2* lds, unsigned t, float2* v) {
  const float4* p = (const float4*)&lds[PHYS(8u * t)];
#pragma unroll
  for (int i = 0; i < 4; i++) {
    float4 f = p[i];
    v[2 * i] = make_float2(f.x, f.y);
    v[2 * i + 1] = make_float2(f.z, f.w);
  }
}

__device__ __forceinline__ float xval(float2 a) {
  float p = a.x * a.x + a.y * a.y;
  return powf(0.8f * tanhf(52428.8f * p), 0.3f);
}

__device__ __forceinline__ void mat_from(const float* s, float2* m) {
  float st, ct, sl, cl, sp, cp, spl, cpl;
  sincosf(0.5f * s[0], &st, &ct);
  sincosf(s[2], &sl, &cl);
  sincosf(s[1], &sp, &cp);
  sincosf(s[1] + s[2], &spl, &cpl);
  m[0] = make_float2(ct, 0.f);
  m[1] = make_float2(-cl * st, -sl * st);
  m[2] = make_float2(cp * st, sp * st);
  m[3] = make_float2(cpl * ct, spl * ct);
}

// TYPE 0 = S1, 1 = S2; INIT synthesizes |0..0>; FINAL does readout.
template <int TYPE, int INIT, int FINAL>
__global__ __launch_bounds__(NT) void pass_k(const float* __restrict__ u3p,
                                             const float* __restrict__ cu3p, int k,
                                             const float2* __restrict__ in,
                                             float2* __restrict__ outPsi,
                                             float* __restrict__ accum,
                                             float* __restrict__ out) {
  __shared__ float2 A[2304], B[2304];  // PHYS(2047)=2301
  __shared__ float2 M[160];            // U3 q at [4q]; CU3 c at [80+4c]
  __shared__ float red[4];
  unsigned t = threadIdx.x, b = blockIdx.x;

  // start psi loads first so they overlap the sincos below
  float2 v[8];
  if (INIT) {
#pragma unroll
    for (int j = 0; j < 8; j++) v[j] = make_float2(0.f, 0.f);
    if (b == 0 && t == 0) { v[0] = make_float2(1.f, 0.f); *accum = 0.f; }
  } else {
    const float4* in4 = (const float4*)in + ((size_t)b << 10) + 4u * t;
#pragma unroll
    for (int i = 0; i < 4; i++) {
      float4 f = in4[i];
      v[2 * i] = make_float2(f.x, f.y);
      v[2 * i + 1] = make_float2(f.z, f.w);
    }
  }

  // this layer's 40 gate matrices
  if (t < 20) mat_from(u3p + (k * 20 + t) * 3, M + 4 * t);
  else if (t >= 64 && t < 84) mat_from(cu3p + (k * 20 + (t - 64)) * 3, M + 80 + 4 * (t - 64));
  __syncthreads();

  const float2* MU = M;
  const float2* MC = M + 80;
  if (TYPE == 0) phase<0, 1, 2, 0, 1>(v, MU, MC);      else phase<-1, 11, 12, 10, 11>(v, MU, MC);
  rot_store(A, t, v); __syncthreads(); rot_load(A, t, v);
  if (TYPE == 0) phase<-1, 3, 4, 2, 3>(v, MU, MC);     else phase<-1, 13, 14, 12, 13>(v, MU, MC);
  rot_store(B, t, v); __syncthreads(); rot_load(B, t, v);
  if (TYPE == 0) phase<-1, 5, 6, 4, 5>(v, MU, MC);     else phase<-1, 15, 16, 14, 15>(v, MU, MC);
  rot_store(A, t, v); __syncthreads(); rot_load(A, t, v);
  if (TYPE == 0) phase<-1, 7, 8, 6, 7>(v, MU, MC);     else phase<-1, 17, 18, 16, 17>(v, MU, MC);
  rot_store(B, t, v); __syncthreads(); rot_load(B, t, v);
  if (TYPE == 0) phase<-1, 9, 10, 8, 9>(v, MU, MC);    else phase<-1, 19, -1, 18, 19>(v, MU, MC);

  // final register layout (rot by 8): m=(w8,w9,w10), t=(w0..w7) of this
  // pass's chain. Next-pass global index (both directions, by symmetry):
  // f4 = blk + 512*t0 + 1024*(t>>1) + 2^17*m0 + 2^18*m1  (pair over m2)
  if (!FINAL) {
    float4* o4 = (float4*)outPsi;
    unsigned base = b + ((t & 1u) << 9) + ((t >> 1) << 10);
    o4[base] = make_float4(v[0].x, v[0].y, v[4].x, v[4].y);
    o4[base + (1u << 17)] = make_float4(v[1].x, v[1].y, v[5].x, v[5].y);
    o4[base + (1u << 18)] = make_float4(v[2].x, v[2].y, v[6].x, v[6].y);
    o4[base + (3u << 17)] = make_float4(v[3].x, v[3].y, v[7].x, v[7].y);
  } else {
    // S2(2) end: m=(q18,q19,q0), t=(q10..q17), blk=(q1..q9).
    // Reference R (bit 19-q): R = m1 + 2*m0 + 4*rev8(t) + 1024*rev9(b) + 2^19*m2
    float xv[8];
    float s = 0.f;
#pragma unroll
    for (int m = 0; m < 8; m++) { xv[m] = xval(v[m]); s += xv[m]; }
    float4* o4 = (float4*)out;
    unsigned base = (__brev(t) >> 24) + ((__brev(b) >> 23) << 8);
    o4[base] = make_float4(xv[0], xv[2], xv[1], xv[3]);
    o4[base + (1u << 17)] = make_float4(xv[4], xv[6], xv[5], xv[7]);
#pragma unroll
    for (int o = 32; o > 0; o >>= 1) s += __shfl_down(s, o);
    if ((t & 63u) == 0) red[t >> 6] = s;
    __syncthreads();
    if (t == 0) atomicAdd(accum, red[0] + red[1] + red[2] + red[3]);
  }
}

__global__ void fin_k(float* __restrict__ out, const float* __restrict__ accum) {
  unsigned i = blockIdx.x * blockDim.x + threadIdx.x;
  float mean = *accum * (1.f / 1048576.f);
  float4* o4 = (float4*)out;
  float4 x = o4[i];
  x.x -= mean; x.y -= mean; x.z -= mean; x.w -= mean;
  o4[i] = x;
}

extern "C" void kernel_launch(void* const* d_in, const int* in_sizes, int n_in,
                              void* d_out, int out_size, void* d_ws, size_t ws_size,
                              hipStream_t stream) {
  const float* u3p = (const float*)d_in[0];
  const float* cu3p = (const float*)d_in[1];
  float* out = (float*)d_out;

  char* ws = (char*)d_ws;
  float2* psiA = (float2*)ws;                              // 8 MB
  float2* psiB = (float2*)(ws + (size_t)8 * 1024 * 1024);  // 8 MB
  float* accum = (float*)(ws + (size_t)16 * 1024 * 1024);

  pass_k<0, 1, 0><<<NB, NT, 0, stream>>>(u3p, cu3p, 0, nullptr, psiB, accum, out);
  pass_k<1, 0, 0><<<NB, NT, 0, stream>>>(u3p, cu3p, 0, psiB, psiA, accum, out);
  pass_k<0, 0, 0><<<NB, NT, 0, stream>>>(u3p, cu3p, 1, psiA, psiB, accum, out);
  pass_k<1, 0, 0><<<NB, NT, 0, stream>>>(u3p, cu3p, 1, psiB, psiA, accum, out);
  pass_k<0, 0, 0><<<NB, NT, 0, stream>>>(u3p, cu3p, 2, psiA, psiB, accum, out);
  pass_k<1, 0, 1><<<NB, NT, 0, stream>>>(u3p, cu3p, 2, psiB, nullptr, accum, out);
  fin_k<<<1024, 256, 0, stream>>>(out, accum);
}